// Round 7
// baseline (3883.422 us; speedup 1.0000x reference)
//
#include <hip/hip_runtime.h>

// GRU + linear readout, B=128 T=2048 IN=32 H=256 L=16.
// 128 blocks x 512 thr (8 waves). Designed to the MEASURED allocator law:
// RF budget = 65536 regs/block (VGPR_Count = 65536/threads, rounds 2-6).
// Weights: z-gate Whh in fp8 e4m3, fully register-resident (2 tiles x 8 kt
// x 2 regs = 32); r/n gates f16 with kt0..3 in regs (64) and kt4..7 in LDS
// (128 KB, streamed ~128 KB/step ~= the LDS-BW floor). Total weight regs 96.
// igates computed in-kernel every 8 steps (M=8-timestep MFMA, Wih JIT from
// L2) into a 12 KB LDS buffer -- no x-side regs in the hot loop, no d_ws.
// Per step: 2-pass MFMA phase (acc 12 regs) -> preacts to LDS -> B1 ->
// gate phase on tid<256 (h single-buffered, fp8+f16 copies) -> B2.

typedef _Float16 half8 __attribute__((ext_vector_type(8)));
typedef float float4v __attribute__((ext_vector_type(4)));

#define TT 2048
#define LOG2E 1.44269504088896f

__device__ __forceinline__ float sigm(float x) {
    return __builtin_amdgcn_rcpf(1.f + __builtin_amdgcn_exp2f(-LOG2E * x));
}
__device__ __forceinline__ float tanhf_(float x) {
    float e = __builtin_amdgcn_exp2f(2.f * LOG2E * x);   // inf-safe: ->1 / ->-1
    return 1.f - 2.f * __builtin_amdgcn_rcpf(e + 1.f);
}
// HW f32->fp8(e4m3,RNE) pack: byte0=cvt(a), byte1=cvt(b)
__device__ __forceinline__ unsigned cvt2_fp8(float a, float b) {
    unsigned r;
    asm("v_cvt_pk_fp8_f32 %0, %1, %2" : "=v"(r) : "v"(a), "v"(b));
    return r & 0xFFFFu;
}

__launch_bounds__(512)
__global__ void gru_kernel(const float* __restrict__ xg,    // [B,T,32]
                           const float* __restrict__ xlin,  // [B,T,16]
                           const float* __restrict__ h0,    // [B,256]
                           const float* __restrict__ Wih,   // [768,32]
                           const float* __restrict__ Whh,   // [768,256]
                           const float* __restrict__ bias,  // [768]
                           const float* __restrict__ biasn, // [256]
                           float* __restrict__ out)         // [B*T]
{
    // LDS: 149,248 B total
    __shared__ _Float16 ldsWr[32768];            // r-gate kt4..7: elem idx = kt*8192 + tile*512 + e
    __shared__ _Float16 ldsWn[32768];            // n-gate kt4..7, same layout
    __shared__ _Float16 ldsIG[8][768];           // igates (incl. bias) for 8 steps
    __shared__ float    pre[768];                // h-side gate preacts
    __shared__ float    ldsBn[256];              // bias_n
    __shared__ __align__(16) _Float16 ldsH[256];          // hidden state f16
    __shared__ __align__(8)  unsigned char ldsH8[256];    // hidden state fp8
    __shared__ __align__(16) _Float16 ldsX[16 * 32];      // x rows for service MFMA

    const int tid  = threadIdx.x;
    const int b    = blockIdx.x;
    const int lane = tid & 63;
    const int w    = tid >> 6;      // wave 0..7
    const int l15  = lane & 15;
    const int lhi  = lane >> 4;     // 0..3 (k-chunk)

    // ---- register weights: wave w owns column groups {2w, 2w+1}
    half8 Wr[2][4], Wn[2][4];
    long  Wz[2][8];
#pragma unroll
    for (int q = 0; q < 2; ++q) {
        const int rowc = (2 * w + q) * 16 + l15;      // column (= Whh row within gate)
#pragma unroll
        for (int kt = 0; kt < 4; ++kt) {              // r,n gates f16, kt0..3
            const float4v* pr = (const float4v*)(Whh + (0   + rowc) * 256 + kt * 32 + lhi * 8);
            const float4v* pn = (const float4v*)(Whh + (512 + rowc) * 256 + kt * 32 + lhi * 8);
            float4v u = pr[0], v2 = pr[1];
            half8 hv;
#pragma unroll
            for (int j = 0; j < 4; ++j) { hv[j] = (_Float16)u[j]; hv[4 + j] = (_Float16)v2[j]; }
            Wr[q][kt] = hv;
            u = pn[0]; v2 = pn[1];
#pragma unroll
            for (int j = 0; j < 4; ++j) { hv[j] = (_Float16)u[j]; hv[4 + j] = (_Float16)v2[j]; }
            Wn[q][kt] = hv;
        }
#pragma unroll
        for (int kt = 0; kt < 8; ++kt) {              // z gate fp8, all kt
            const float* pz = Whh + (256 + rowc) * 256 + kt * 32 + lhi * 8;
            unsigned long p0 = cvt2_fp8(pz[0], pz[1]);
            unsigned long p1 = cvt2_fp8(pz[2], pz[3]);
            unsigned long p2 = cvt2_fp8(pz[4], pz[5]);
            unsigned long p3 = cvt2_fp8(pz[6], pz[7]);
            Wz[q][kt] = (long)(p0 | (p1 << 16) | (p2 << 32) | (p3 << 48));
        }
    }

    // ---- stage r/n kt4..7 into LDS (elem idx c: kt=c>>13, tile=(c>>9)&15, e=c&511)
    for (int c = tid; c < 32768; c += 512) {
        const int kt = c >> 13, tile = (c >> 9) & 15, e = c & 511;
        const int row = tile * 16 + (e >> 5);
        const int k   = (kt + 4) * 32 + (e & 31);
        ldsWr[c] = (_Float16)Whh[(0   + row) * 256 + k];
        ldsWn[c] = (_Float16)Whh[(512 + row) * 256 + k];
    }

    // ---- init h, bias_n, zero top half of x-stage
    if (tid < 256) {
        float hv = h0[b * 256 + tid];
        ldsH[tid]  = (_Float16)hv;
        ldsH8[tid] = (unsigned char)(cvt2_fp8(hv, 0.f) & 0xFF);
        ldsBn[tid] = biasn[tid];
        ldsX[256 + tid] = (_Float16)0.f;              // rows 8..15 = 0
    }
    float xlc = 0.f;
    if (tid < 16) xlc = xlin[(size_t)b * TT * 16 + tid];
    __syncthreads();

    const int wrbase = w * 2048 + l15 * 64 + lhi * 16;   // byte base in ldsWr/ldsWn (q=0)
    const float4v zero4 = {0.f, 0.f, 0.f, 0.f};

#pragma clang loop unroll(disable)
    for (int t = 0; t < TT; ++t) {
        // ---- service phase: every 8 steps compute igates for t..t+7
        if ((t & 7) == 0) {
            if (tid < 256) {
                const int tt = tid >> 5, k = tid & 31;
                ldsX[tt * 32 + k] = (_Float16)xg[((size_t)b * TT + t + tt) * 32 + k];
            }
            __syncthreads();
            const half8 axv = *(const half8*)((const char*)ldsX + l15 * 64 + lhi * 16);
#pragma unroll
            for (int g = 0; g < 3; ++g) {
#pragma unroll
                for (int q = 0; q < 2; ++q) {
                    const int tg = g * 16 + 2 * w + q;          // global tile 0..47
                    const float4v* pp = (const float4v*)(Wih + (tg * 16 + l15) * 32 + lhi * 8);
                    float4v u = pp[0], v2 = pp[1];
                    half8 wx;
#pragma unroll
                    for (int j = 0; j < 4; ++j) { wx[j] = (_Float16)u[j]; wx[4 + j] = (_Float16)v2[j]; }
                    float4v d = __builtin_amdgcn_mfma_f32_16x16x32_f16(axv, wx, zero4, 0, 0, 0);
                    const float bb = bias[tg * 16 + l15];
                    if (lhi < 2) {                              // rows 0..7 = timesteps
#pragma unroll
                        for (int rg = 0; rg < 4; ++rg)
                            ldsIG[lhi * 4 + rg][tg * 16 + l15] = (_Float16)(d[rg] + bb);
                    }
                }
            }
            // ig writes are consumed only after B1 below -> no extra barrier
        }

        // prefetch next xl (covered by MFMA phase)
        float xln = 0.f;
        if (tid < 16) xln = xlin[((size_t)b * TT + (t + 1 < TT ? t + 1 : t)) * 16 + tid];

        // ---- MFMA phase: 2 passes over column groups q
#pragma unroll
        for (int q = 0; q < 2; ++q) {
            float4v aR = zero4, aZ = zero4, aN = zero4;
#pragma unroll
            for (int kt = 0; kt < 8; ++kt) {
                half8 hf = *(const half8*)((const char*)ldsH + kt * 64 + lhi * 16);
                long  h8 = *(const long*)((const char*)ldsH8 + kt * 32 + lhi * 8);
                half8 br = (kt < 4) ? Wr[q][kt]
                    : *(const half8*)((const char*)ldsWr + (kt - 4) * 16384 + q * 1024 + wrbase);
                half8 bn8 = (kt < 4) ? Wn[q][kt]
                    : *(const half8*)((const char*)ldsWn + (kt - 4) * 16384 + q * 1024 + wrbase);
                aR = __builtin_amdgcn_mfma_f32_16x16x32_f16(hf, br, aR, 0, 0, 0);
                aZ = __builtin_amdgcn_mfma_f32_16x16x32_fp8_fp8(h8, Wz[q][kt], aZ, 0, 0, 0);
                aN = __builtin_amdgcn_mfma_f32_16x16x32_f16(hf, bn8, aN, 0, 0, 0);
            }
            if (lane < 16) {                          // row 0 = the real batch row
                const int cc = (2 * w + q) * 16 + l15;
                pre[cc]       = aR[0];
                pre[256 + cc] = aZ[0];
                pre[512 + cc] = aN[0];
            }
        }
        __syncthreads();   // B1: preacts + (every 8th step) igates visible

        // ---- gate phase
        if (tid < 256) {
            const int c = tid;
            const int t8 = t & 7;
            float rr = sigm(pre[c]       + (float)ldsIG[t8][c]);
            float zz = sigm(pre[256 + c] + (float)ldsIG[t8][256 + c]);
            float nn = tanhf_((float)ldsIG[t8][512 + c] + rr * (pre[512 + c] + ldsBn[c]));
            float hold = (float)ldsH[c];
            float hnew = nn + zz * (hold - nn);
            ldsH[c]  = (_Float16)hnew;
            ldsH8[c] = (unsigned char)(cvt2_fp8(hnew, 0.f) & 0xFF);
            if (c < 16) {
                float v = hnew * xlc;
                v += __shfl_xor(v, 8, 16);
                v += __shfl_xor(v, 4, 16);
                v += __shfl_xor(v, 2, 16);
                v += __shfl_xor(v, 1, 16);
                if (c == 0) out[(size_t)b * TT + t] = v;
            }
        }
        xlc = xln;
        __syncthreads();   // B2: new h visible for next step's MFMA phase
    }
}

extern "C" void kernel_launch(void* const* d_in, const int* in_sizes, int n_in,
                              void* d_out, int out_size, void* d_ws, size_t ws_size,
                              hipStream_t stream) {
    const float* xg    = (const float*)d_in[0];
    const float* xlin  = (const float*)d_in[1];
    const float* h0    = (const float*)d_in[2];
    const float* Wih   = (const float*)d_in[3];
    const float* Whh   = (const float*)d_in[4];
    const float* bias  = (const float*)d_in[5];
    const float* biasn = (const float*)d_in[6];
    float* out = (float*)d_out;

    gru_kernel<<<128, 512, 0, stream>>>(xg, xlin, h0, Wih, Whh, bias, biasn, out);
}

// Round 8
// 3634.840 us; speedup vs baseline: 1.0684x; 1.0684x over previous
//
#include <hip/hip_runtime.h>

// GRU + linear readout, B=128 T=2048 IN=32 H=256 L=16.
// 128 blocks x 512 thr (8 waves). RF law (rounds 2-7): 65536 regs/block ->
// 128 VGPR/lane; 96 weight regs fits (validated round 7, no spill).
// Weights: r,z gates fp8 e4m3 fully register-resident (16+16 longs);
// n gate f16, kt0..3 in regs (32) + kt4..7 streamed from LDS in
// FRAGMENT-ORDERED layout (byte = kt_rel*16384 + tile*1024 + lane*16) so
// each wave's ds_read_b128 covers 1024 contiguous bytes -> conflict-free
// (round 7's l15*64+lhi*16 base was an 8-way conflict, 1.4e8 cycles).
// igates computed in-kernel every 8 steps (M=8 timestep-rows MFMA, Wih JIT
// from L2) into LDS. Per step: MFMA phase (r/z fp8 + n f16, 48 MFMA/wave)
// -> preacts to LDS -> B1 -> gate phase on tid<256 -> B2.

typedef _Float16 half8 __attribute__((ext_vector_type(8)));
typedef float float4v __attribute__((ext_vector_type(4)));

#define TT 2048
#define LOG2E 1.44269504088896f

__device__ __forceinline__ float sigm(float x) {
    return __builtin_amdgcn_rcpf(1.f + __builtin_amdgcn_exp2f(-LOG2E * x));
}
__device__ __forceinline__ float tanhf_(float x) {
    float e = __builtin_amdgcn_exp2f(2.f * LOG2E * x);   // inf-safe: ->1 / ->-1
    return 1.f - 2.f * __builtin_amdgcn_rcpf(e + 1.f);
}
// HW f32->fp8(e4m3,RNE) pack: byte0=cvt(a), byte1=cvt(b)
__device__ __forceinline__ unsigned cvt2_fp8(float a, float b) {
    unsigned r;
    asm("v_cvt_pk_fp8_f32 %0, %1, %2" : "=v"(r) : "v"(a), "v"(b));
    return r & 0xFFFFu;
}
__device__ __forceinline__ long pack_fp8_row(const float* p) {
    unsigned long p0 = cvt2_fp8(p[0], p[1]);
    unsigned long p1 = cvt2_fp8(p[2], p[3]);
    unsigned long p2 = cvt2_fp8(p[4], p[5]);
    unsigned long p3 = cvt2_fp8(p[6], p[7]);
    return (long)(p0 | (p1 << 16) | (p2 << 32) | (p3 << 48));
}

__launch_bounds__(512)
__global__ void gru_kernel(const float* __restrict__ xg,    // [B,T,32]
                           const float* __restrict__ xlin,  // [B,T,16]
                           const float* __restrict__ h0,    // [B,256]
                           const float* __restrict__ Wih,   // [768,32]
                           const float* __restrict__ Whh,   // [768,256]
                           const float* __restrict__ bias,  // [768]
                           const float* __restrict__ biasn, // [256]
                           float* __restrict__ out)         // [B*T]
{
    // LDS ~82 KB
    __shared__ _Float16 ldsWn[32768];            // n-gate kt4..7, fragment-ordered
    __shared__ _Float16 ldsIG[8][768];           // igates (incl. bias) for 8 steps
    __shared__ float    pre[768];                // h-side gate preacts
    __shared__ float    ldsBn[256];              // bias_n
    __shared__ __align__(16) _Float16 ldsH[256];          // hidden state f16
    __shared__ __align__(8)  unsigned char ldsH8[256];    // hidden state fp8
    __shared__ __align__(16) _Float16 ldsX[16 * 32];      // x rows for service MFMA

    const int tid  = threadIdx.x;
    const int b    = blockIdx.x;
    const int lane = tid & 63;
    const int w    = tid >> 6;      // wave 0..7
    const int l15  = lane & 15;
    const int lhi  = lane >> 4;     // 0..3 (k-chunk)

    // ---- register weights: wave w owns column groups {2w, 2w+1}
    long  Wr8[2][8], Wz8[2][8];     // fp8 e4m3, all 8 k-tiles
    half8 Wn[2][4];                 // f16, k-tiles 0..3
#pragma unroll
    for (int q = 0; q < 2; ++q) {
        const int rowc = (2 * w + q) * 16 + l15;      // column within gate
#pragma unroll
        for (int kt = 0; kt < 8; ++kt) {
            Wr8[q][kt] = pack_fp8_row(Whh + (0   + rowc) * 256 + kt * 32 + lhi * 8);
            Wz8[q][kt] = pack_fp8_row(Whh + (256 + rowc) * 256 + kt * 32 + lhi * 8);
        }
#pragma unroll
        for (int kt = 0; kt < 4; ++kt) {
            const float4v* pn = (const float4v*)(Whh + (512 + rowc) * 256 + kt * 32 + lhi * 8);
            float4v u = pn[0], v2 = pn[1];
            half8 hv;
#pragma unroll
            for (int j = 0; j < 4; ++j) { hv[j] = (_Float16)u[j]; hv[4 + j] = (_Float16)v2[j]; }
            Wn[q][kt] = hv;
        }
    }

    // ---- stage n-gate kt4..7 into LDS, fragment-ordered, conflict-free
    //      chunk c (16B): kt=c>>10, tile=(c&1023)>>6, ln=c&63;
    //      content = Whh_n[row=tile*16+(ln&15)][k=(kt+4)*32+(ln>>4)*8 ..+8]
    for (int c = tid; c < 4096; c += 512) {
        const int kt = c >> 10, rem = c & 1023;
        const int tile = rem >> 6, ln = rem & 63;
        const int row  = tile * 16 + (ln & 15);
        const int k    = (kt + 4) * 32 + (ln >> 4) * 8;
        const float* p = Whh + (512 + row) * 256 + k;
        half8 v;
#pragma unroll
        for (int j = 0; j < 8; ++j) v[j] = (_Float16)p[j];
        *(half8*)((char*)ldsWn + c * 16) = v;
    }

    // ---- init h, bias_n, zero rows 8..15 of x-stage
    if (tid < 256) {
        float hv = h0[b * 256 + tid];
        ldsH[tid]  = (_Float16)hv;
        ldsH8[tid] = (unsigned char)(cvt2_fp8(hv, 0.f) & 0xFF);
        ldsBn[tid] = biasn[tid];
        ldsX[256 + tid] = (_Float16)0.f;
    }
    float xlc = 0.f;
    if (tid < 16) xlc = xlin[(size_t)b * TT * 16 + tid];
    __syncthreads();

    const int wnbase = lane * 16;                 // + q*1024 + (2w)*1024 + kt_rel*16384
    const float4v zero4 = {0.f, 0.f, 0.f, 0.f};

#pragma clang loop unroll(disable)
    for (int t = 0; t < TT; ++t) {
        // ---- service phase: every 8 steps compute igates for t..t+7
        if ((t & 7) == 0) {
            if (tid < 256) {
                const int tt = tid >> 5, k = tid & 31;
                ldsX[tt * 32 + k] = (_Float16)xg[((size_t)b * TT + t + tt) * 32 + k];
            }
            __syncthreads();
            const half8 axv = *(const half8*)((const char*)ldsX + l15 * 64 + lhi * 16);
#pragma unroll
            for (int g = 0; g < 3; ++g) {
#pragma unroll
                for (int q = 0; q < 2; ++q) {
                    const int tg = g * 16 + 2 * w + q;          // global tile 0..47
                    const float4v* pp = (const float4v*)(Wih + (tg * 16 + l15) * 32 + lhi * 8);
                    float4v u = pp[0], v2 = pp[1];
                    half8 wx;
#pragma unroll
                    for (int j = 0; j < 4; ++j) { wx[j] = (_Float16)u[j]; wx[4 + j] = (_Float16)v2[j]; }
                    float4v d = __builtin_amdgcn_mfma_f32_16x16x32_f16(axv, wx, zero4, 0, 0, 0);
                    const float bb = bias[tg * 16 + l15];
                    if (lhi < 2) {                              // rows 0..7 = timesteps
#pragma unroll
                        for (int rg = 0; rg < 4; ++rg)
                            ldsIG[lhi * 4 + rg][tg * 16 + l15] = (_Float16)(d[rg] + bb);
                    }
                }
            }
            // ig writes consumed only after B1 below -> no extra barrier
        }

        // prefetch next xl (covered by MFMA phase)
        float xln = 0.f;
        if (tid < 16) xln = xlin[((size_t)b * TT + (t + 1 < TT ? t + 1 : t)) * 16 + tid];

        // ---- MFMA phase: 2 passes over column groups q
#pragma unroll
        for (int q = 0; q < 2; ++q) {
            float4v aR = zero4, aZ = zero4, aN = zero4;
#pragma unroll
            for (int kt = 0; kt < 8; ++kt) {
                long  h8 = *(const long*)((const char*)ldsH8 + kt * 32 + lhi * 8);
                half8 hf = *(const half8*)((const char*)ldsH + kt * 64 + lhi * 16);
                half8 bn8;
                if (kt < 4) bn8 = Wn[q][kt];
                else        bn8 = *(const half8*)((const char*)ldsWn
                                    + (kt - 4) * 16384 + (2 * w + q) * 1024 + wnbase);
                aR = __builtin_amdgcn_mfma_f32_16x16x32_fp8_fp8(h8, Wr8[q][kt], aR, 0, 0, 0);
                aZ = __builtin_amdgcn_mfma_f32_16x16x32_fp8_fp8(h8, Wz8[q][kt], aZ, 0, 0, 0);
                aN = __builtin_amdgcn_mfma_f32_16x16x32_f16(hf, bn8, aN, 0, 0, 0);
            }
            if (lane < 16) {                          // row 0 = the real batch row
                const int cc = (2 * w + q) * 16 + l15;
                pre[cc]       = aR[0];
                pre[256 + cc] = aZ[0];
                pre[512 + cc] = aN[0];
            }
        }
        __syncthreads();   // B1: preacts + (every 8th step) igates visible

        // ---- gate phase
        if (tid < 256) {
            const int c = tid;
            const int t8 = t & 7;
            float rr = sigm(pre[c]       + (float)ldsIG[t8][c]);
            float zz = sigm(pre[256 + c] + (float)ldsIG[t8][256 + c]);
            float nn = tanhf_((float)ldsIG[t8][512 + c] + rr * (pre[512 + c] + ldsBn[c]));
            float hold = (float)ldsH[c];
            float hnew = nn + zz * (hold - nn);
            ldsH[c]  = (_Float16)hnew;
            ldsH8[c] = (unsigned char)(cvt2_fp8(hnew, 0.f) & 0xFF);
            if (c < 16) {
                float v = hnew * xlc;
                v += __shfl_xor(v, 8, 16);
                v += __shfl_xor(v, 4, 16);
                v += __shfl_xor(v, 2, 16);
                v += __shfl_xor(v, 1, 16);
                if (c == 0) out[(size_t)b * TT + t] = v;
            }
        }
        xlc = xln;
        __syncthreads();   // B2: new h visible for next step's MFMA phase
    }
}

extern "C" void kernel_launch(void* const* d_in, const int* in_sizes, int n_in,
                              void* d_out, int out_size, void* d_ws, size_t ws_size,
                              hipStream_t stream) {
    const float* xg    = (const float*)d_in[0];
    const float* xlin  = (const float*)d_in[1];
    const float* h0    = (const float*)d_in[2];
    const float* Wih   = (const float*)d_in[3];
    const float* Whh   = (const float*)d_in[4];
    const float* bias  = (const float*)d_in[5];
    const float* biasn = (const float*)d_in[6];
    float* out = (float*)d_out;

    gru_kernel<<<128, 512, 0, stream>>>(xg, xlin, h0, Wih, Whh, bias, biasn, out);
}

// Round 10
// 3362.517 us; speedup vs baseline: 1.1549x; 1.0810x over previous
//
#include <hip/hip_runtime.h>

// GRU + linear readout, B=128 T=2048 IN=32 H=256 L=16.
// 128 blocks x 256 thr (4 waves). Allocator law (r2-r8): 65536 regs/block ->
// 256 VGPR/lane at 256 thr. Wave w owns cols [64w,64w+64): 4 tiles/gate.
// Weights: r,z fp8 e4m3 fully register-resident (64+64 regs), n f16 kt0..3
// resident (64) + kt4..7 streamed from LDS fragment-ordered (conflict-free).
// Census ~241 < 256 -> no spill. Gate phase wave-local via shfl gather.
// h/h8 DOUBLE-BUFFERED in LDS (race fix for round 9: single-buffered h with
// one barrier let fast waves overwrite h while slow waves still read it).
// ONE barrier/step. igates computed every 8 steps from LDS-staged Wih.

typedef _Float16 half8 __attribute__((ext_vector_type(8)));
typedef float float4v __attribute__((ext_vector_type(4)));

#define TT 2048
#define LOG2E 1.44269504088896f

__device__ __forceinline__ float sigm(float x) {
    return __builtin_amdgcn_rcpf(1.f + __builtin_amdgcn_exp2f(-LOG2E * x));
}
__device__ __forceinline__ float tanhf_(float x) {
    float e = __builtin_amdgcn_exp2f(2.f * LOG2E * x);   // inf-safe: ->1 / ->-1
    return 1.f - 2.f * __builtin_amdgcn_rcpf(e + 1.f);
}
// HW f32->fp8(e4m3,RNE) pack
__device__ __forceinline__ unsigned cvt2_fp8(float a, float b) {
    unsigned r;
    asm("v_cvt_pk_fp8_f32 %0, %1, %2" : "=v"(r) : "v"(a), "v"(b));
    return r & 0xFFFFu;
}
__device__ __forceinline__ long pack_fp8_row(const float* p) {
    unsigned long p0 = cvt2_fp8(p[0], p[1]);
    unsigned long p1 = cvt2_fp8(p[2], p[3]);
    unsigned long p2 = cvt2_fp8(p[4], p[5]);
    unsigned long p3 = cvt2_fp8(p[6], p[7]);
    return (long)(p0 | (p1 << 16) | (p2 << 32) | (p3 << 48));
}

__launch_bounds__(256)
__global__ void gru_kernel(const float* __restrict__ xg,    // [B,T,32]
                           const float* __restrict__ xlin,  // [B,T,16]
                           const float* __restrict__ h0,    // [B,256]
                           const float* __restrict__ Wih,   // [768,32]
                           const float* __restrict__ Whh,   // [768,256]
                           const float* __restrict__ bias,  // [768]
                           const float* __restrict__ biasn, // [256]
                           float* __restrict__ out)         // [B*T]
{
    // LDS ~127 KB, weight arrays fragment-ordered (wave reads 1024B contiguous)
    __shared__ _Float16 ldsWn[32768];   // 64KB: n-gate kt4..7; byte=(kt-4)*16384+tile*1024+ln*16
    __shared__ _Float16 ldsWx[24576];   // 48KB: Wih; byte=tile*1024+ln*16
    __shared__ _Float16 ldsIG[8][768];  // 12KB: x-side preacts (no bias) for 8 steps
    __shared__ __align__(16) _Float16 ldsH[2][256];        // hidden f16, double-buffered
    __shared__ __align__(8)  unsigned char ldsH8[2][256];  // hidden fp8, double-buffered
    __shared__ __align__(16) _Float16 ldsX[512];           // 16 x-rows for service MFMA

    const int tid  = threadIdx.x;
    const int b    = blockIdx.x;
    const int lane = tid & 63;
    const int w    = tid >> 6;      // wave 0..3
    const int l15  = lane & 15;
    const int lhi  = lane >> 4;     // 0..3

    // ---- register weights: wave w owns tiles {w*4+q}, q=0..3, per gate
    long  Wr8[4][8], Wz8[4][8];     // fp8, all k
    half8 Wn[4][4];                 // f16, kt0..3
#pragma unroll
    for (int q = 0; q < 4; ++q) {
        const int rowc = (w * 4 + q) * 16 + l15;
#pragma unroll
        for (int kt = 0; kt < 8; ++kt) {
            Wr8[q][kt] = pack_fp8_row(Whh + (0   + rowc) * 256 + kt * 32 + lhi * 8);
            Wz8[q][kt] = pack_fp8_row(Whh + (256 + rowc) * 256 + kt * 32 + lhi * 8);
        }
#pragma unroll
        for (int kt = 0; kt < 4; ++kt) {
            const float4v* pn = (const float4v*)(Whh + (512 + rowc) * 256 + kt * 32 + lhi * 8);
            float4v u = pn[0], v2 = pn[1];
            half8 hv;
#pragma unroll
            for (int j = 0; j < 4; ++j) { hv[j] = (_Float16)u[j]; hv[4 + j] = (_Float16)v2[j]; }
            Wn[q][kt] = hv;
        }
    }

    // ---- stage n-gate kt4..7 (fragment-ordered, conflict-free)
    for (int c = tid; c < 4096; c += 256) {
        const int kt = c >> 10, rem = c & 1023;
        const int tile = rem >> 6, ln = rem & 63;
        const int row  = tile * 16 + (ln & 15);
        const int k    = (kt + 4) * 32 + (ln >> 4) * 8;
        const float* p = Whh + (512 + row) * 256 + k;
        half8 v;
#pragma unroll
        for (int j = 0; j < 8; ++j) v[j] = (_Float16)p[j];
        *(half8*)((char*)ldsWn + c * 16) = v;
    }
    // ---- stage Wih (fragment-ordered)
    for (int c = tid; c < 3072; c += 256) {
        const int tile = c >> 6, ln = c & 63;
        const int row  = tile * 16 + (ln & 15);
        const int k    = (ln >> 4) * 8;
        const float* p = Wih + row * 32 + k;
        half8 v;
#pragma unroll
        for (int j = 0; j < 8; ++j) v[j] = (_Float16)p[j];
        *(half8*)((char*)ldsWx + c * 16) = v;
    }

    // ---- per-thread state (col = tid)
    const float b_r = bias[tid];
    const float b_z = bias[256 + tid];
    const float b_i = bias[512 + tid];
    const float b_n = biasn[tid];
    float hreg = h0[b * 256 + tid];
    ldsH[0][tid]  = (_Float16)hreg;
    ldsH8[0][tid] = (unsigned char)(cvt2_fp8(hreg, 0.f) & 0xFF);
    ldsX[256 + tid] = (_Float16)0.f;               // zero-pad rows 8..15
    float xlc = 0.f;
    if (w == 0 && lane < 16) xlc = xlin[(size_t)b * TT * 16 + lane];
    __syncthreads();

    const float4v zero4 = {0.f, 0.f, 0.f, 0.f};

#pragma clang loop unroll(disable)
    for (int t = 0; t < TT; ++t) {
        const int p = t & 1;

        // ---- service: every 8 steps, igates for t..t+7 (wave-local columns)
        if ((t & 7) == 0) {
            ldsX[tid] = (_Float16)xg[((size_t)b * TT + t + (tid >> 5)) * 32 + (tid & 31)];
            __syncthreads();
            const half8 axv = *(const half8*)((const char*)ldsX + l15 * 64 + lhi * 16);
#pragma unroll
            for (int g = 0; g < 3; ++g) {
#pragma unroll
                for (int q = 0; q < 4; ++q) {
                    half8 wx = *(const half8*)((const char*)ldsWx
                                   + (g * 16 + w * 4 + q) * 1024 + lane * 16);
                    float4v d = __builtin_amdgcn_mfma_f32_16x16x32_f16(axv, wx, zero4, 0, 0, 0);
                    if (lhi < 2) {                 // rows 0..7 = timesteps
#pragma unroll
                        for (int rg = 0; rg < 4; ++rg)
                            ldsIG[lhi * 4 + rg][g * 256 + (w * 4 + q) * 16 + l15] = (_Float16)d[rg];
                    }
                }
            }
            // IG consumed by the SAME wave below; in-wave DS ordering suffices
        }

        // ---- prefetch this step's igates + next xl (hidden under MFMAs)
        const int t8 = t & 7;
        float igr = (float)ldsIG[t8][tid];
        float igz = (float)ldsIG[t8][256 + tid];
        float ign = (float)ldsIG[t8][512 + tid];
        float xln = 0.f;
        if (w == 0 && lane < 16) xln = xlin[((size_t)b * TT + (t + 1 < TT ? t + 1 : t)) * 16 + lane];

        // ---- MFMA phase: 4 passes (one 16-col group each), read h buffer p
        float sR[4], sZ[4], sN[4];
#pragma unroll
        for (int q = 0; q < 4; ++q) {
            float4v aR = zero4, aZ = zero4, aN = zero4;
#pragma unroll
            for (int kt = 0; kt < 8; ++kt) {
                long  h8 = *(const long*)((const char*)&ldsH8[p][0] + kt * 32 + lhi * 8);
                half8 hf = *(const half8*)((const char*)&ldsH[p][0] + kt * 64 + lhi * 16);
                half8 bn8;
                if (kt < 4) bn8 = Wn[q][kt];
                else        bn8 = *(const half8*)((const char*)ldsWn
                                      + (kt - 4) * 16384 + (w * 4 + q) * 1024 + lane * 16);
                aR = __builtin_amdgcn_mfma_f32_16x16x32_fp8_fp8(h8, Wr8[q][kt], aR, 0, 0, 0);
                aZ = __builtin_amdgcn_mfma_f32_16x16x32_fp8_fp8(h8, Wz8[q][kt], aZ, 0, 0, 0);
                aN = __builtin_amdgcn_mfma_f32_16x16x32_f16(hf, bn8, aN, 0, 0, 0);
            }
            sR[q] = aR[0]; sZ[q] = aZ[0]; sN[q] = aN[0];   // all rows equal; col = l15
        }

        // ---- gather: lane l (col w*64+l) needs pass q=lhi from lane l15
        float pR, pZ, pN;
        {
            float r0 = __shfl(sR[0], l15, 64), r1 = __shfl(sR[1], l15, 64);
            float r2 = __shfl(sR[2], l15, 64), r3 = __shfl(sR[3], l15, 64);
            pR = lhi == 0 ? r0 : lhi == 1 ? r1 : lhi == 2 ? r2 : r3;
            float z0 = __shfl(sZ[0], l15, 64), z1 = __shfl(sZ[1], l15, 64);
            float z2 = __shfl(sZ[2], l15, 64), z3 = __shfl(sZ[3], l15, 64);
            pZ = lhi == 0 ? z0 : lhi == 1 ? z1 : lhi == 2 ? z2 : z3;
            float n0 = __shfl(sN[0], l15, 64), n1 = __shfl(sN[1], l15, 64);
            float n2 = __shfl(sN[2], l15, 64), n3 = __shfl(sN[3], l15, 64);
            pN = lhi == 0 ? n0 : lhi == 1 ? n1 : lhi == 2 ? n2 : n3;
        }

        // ---- gates (per-thread, col = tid); write h buffer p^1
        float rr = sigm(pR + igr + b_r);
        float zz = sigm(pZ + igz + b_z);
        float nn = tanhf_(ign + b_i + rr * (pN + b_n));
        float hnew = nn + zz * (hreg - nn);
        hreg = hnew;
        ldsH[p ^ 1][tid]  = (_Float16)hnew;
        ldsH8[p ^ 1][tid] = (unsigned char)(cvt2_fp8(hnew, 0.f) & 0xFF);

        // ---- readout: cols 0..15 = lanes 0..15 of wave 0
        if (w == 0) {
            float v = hnew * xlc;
            v += __shfl_xor(v, 8, 16);
            v += __shfl_xor(v, 4, 16);
            v += __shfl_xor(v, 2, 16);
            v += __shfl_xor(v, 1, 16);
            if (lane == 0) out[(size_t)b * TT + t] = v;
        }

        xlc = xln;
        __syncthreads();   // B: h buffer p^1 complete before step t+1 reads it
    }
}

extern "C" void kernel_launch(void* const* d_in, const int* in_sizes, int n_in,
                              void* d_out, int out_size, void* d_ws, size_t ws_size,
                              hipStream_t stream) {
    const float* xg    = (const float*)d_in[0];
    const float* xlin  = (const float*)d_in[1];
    const float* h0    = (const float*)d_in[2];
    const float* Wih   = (const float*)d_in[3];
    const float* Whh   = (const float*)d_in[4];
    const float* bias  = (const float*)d_in[5];
    const float* biasn = (const float*)d_in[6];
    float* out = (float*)d_out;

    gru_kernel<<<128, 256, 0, stream>>>(xg, xlin, h0, Wih, Whh, bias, biasn, out);
}